// Round 5
// baseline (699.664 us; speedup 1.0000x reference)
//
#include <hip/hip_runtime.h>
#include <math.h>

#define N_NODES 20000
#define N_EDGES 640000
#define E_TOT   (N_EDGES + N_NODES)
#define HD 256
#define NH 8
#define CH 32
#define NB 4096
#define NM 8

typedef short bf16x8 __attribute__((ext_vector_type(8)));
typedef float f32x4  __attribute__((ext_vector_type(4)));

__device__ __forceinline__ ushort f2bf(float f) {   // RNE
  uint u = __float_as_uint(f);
  u += 0x7FFFu + ((u >> 16) & 1u);
  return (ushort)(u >> 16);
}
__device__ __forceinline__ float bf2f(ushort s) {
  return __uint_as_float(((uint)s) << 16);
}

// ---- weight transpose+convert: WT[n][k] = bf16(W[k][n]) ----
__global__ __launch_bounds__(256) void k_wtrans(
    const float* __restrict__ W, ushort* __restrict__ WT,
    int K, int N, int strideW, int strideWT)
{
  __shared__ float tile[64][65];
  const float* Wp = W + (size_t)blockIdx.z * strideW;
  ushort* WTp = WT + (size_t)blockIdx.z * strideWT;
  int n0 = blockIdx.x * 64, k0 = blockIdx.y * 64;
  int t = threadIdx.x;
  int c = t & 63, r0 = (t >> 6) * 16;
#pragma unroll
  for (int i = 0; i < 16; ++i)
    tile[r0 + i][c] = Wp[(size_t)(k0 + r0 + i) * N + n0 + c];
  __syncthreads();
#pragma unroll
  for (int i = 0; i < 16; ++i)
    WTp[(size_t)(n0 + r0 + i) * K + k0 + c] = f2bf(tile[c][r0 + i]);
}

// ---- bf16 MFMA GEMM: 128x128 tile, 4 waves (2x2 of 64x64), register-prefetch pipelined ----
// MODE 0: A fp32 (converted in staging); out = Cf fp32 (+bias) AND Cb bf16
// MODE 1: A bf16; out = Cb bf16 only
template<int MODE>
__global__ __launch_bounds__(256, 2) void k_gemm_mfma(
    const void* __restrict__ Ain, const ushort* __restrict__ BT,
    const float* __restrict__ bias, float* __restrict__ Cf,
    ushort* __restrict__ Cb, int M, int K)
{
  __shared__ ushort As[128 * 32];
  __shared__ ushort Bs[128 * 32];
  const int t = threadIdx.x;
  const int n0 = blockIdx.x * 128;
  const int m0 = blockIdx.y * 128;
  const int wave = t >> 6, lane = t & 63;
  const int wm = (wave & 1) * 64, wn = (wave >> 1) * 64;
  const int lm = lane & 15, quad = lane >> 4;

  f32x4 acc[4][4];
#pragma unroll
  for (int mi = 0; mi < 4; ++mi)
#pragma unroll
    for (int ni = 0; ni < 4; ++ni) acc[mi][ni] = (f32x4){0.f, 0.f, 0.f, 0.f};

  // per-cch staging geometry
  int rowc[2], jc[2], arc[2];
#pragma unroll
  for (int cch = 0; cch < 2; ++cch) {
    int id = t + cch * 256;
    rowc[cch] = id >> 2;
    jc[cch]   = id & 3;
    arc[cch]  = min(m0 + rowc[cch], M - 1);
  }

  float4 pa0[2], pa1[2];   // MODE 0 prefetch (fp32)
  uint4  paB[2];           // MODE 1 prefetch (bf16)
  uint4  pb[2];            // B prefetch

#define LOAD_TILE(K0)                                                          \
  {                                                                            \
    _Pragma("unroll")                                                          \
    for (int cch = 0; cch < 2; ++cch) {                                        \
      if (MODE == 0) {                                                         \
        const float* src = (const float*)Ain + (size_t)arc[cch] * K + (K0) + jc[cch] * 8; \
        pa0[cch] = *(const float4*)src;                                        \
        pa1[cch] = *(const float4*)(src + 4);                                  \
      } else {                                                                 \
        const ushort* src = (const ushort*)Ain + (size_t)arc[cch] * K + (K0) + jc[cch] * 8; \
        paB[cch] = *(const uint4*)src;                                         \
      }                                                                        \
      pb[cch] = *(const uint4*)(BT + (size_t)(n0 + rowc[cch]) * K + (K0) + jc[cch] * 8); \
    }                                                                          \
  }

  LOAD_TILE(0);

  for (int k0 = 0; k0 < K; k0 += 32) {
    // store prefetched tile to LDS
#pragma unroll
    for (int cch = 0; cch < 2; ++cch) {
      int row = rowc[cch];
      int sw = (jc[cch] ^ (row & 3)) * 8;
      if (MODE == 0) {
        uint4 p;
        p.x = (uint)f2bf(pa0[cch].x) | ((uint)f2bf(pa0[cch].y) << 16);
        p.y = (uint)f2bf(pa0[cch].z) | ((uint)f2bf(pa0[cch].w) << 16);
        p.z = (uint)f2bf(pa1[cch].x) | ((uint)f2bf(pa1[cch].y) << 16);
        p.w = (uint)f2bf(pa1[cch].z) | ((uint)f2bf(pa1[cch].w) << 16);
        *(uint4*)&As[row * 32 + sw] = p;
      } else {
        *(uint4*)&As[row * 32 + sw] = paB[cch];
      }
      *(uint4*)&Bs[row * 32 + sw] = pb[cch];
    }
    __syncthreads();
    if (k0 + 32 < K) LOAD_TILE(k0 + 32);   // overlap next global load with MFMA

    bf16x8 af[4], bfr[4];
#pragma unroll
    for (int mi = 0; mi < 4; ++mi) {
      int row = wm + mi * 16 + lm;
      af[mi] = *(const bf16x8*)&As[row * 32 + ((quad ^ (row & 3)) << 3)];
    }
#pragma unroll
    for (int ni = 0; ni < 4; ++ni) {
      int row = wn + ni * 16 + lm;
      bfr[ni] = *(const bf16x8*)&Bs[row * 32 + ((quad ^ (row & 3)) << 3)];
    }
#pragma unroll
    for (int mi = 0; mi < 4; ++mi)
#pragma unroll
      for (int ni = 0; ni < 4; ++ni)
        acc[mi][ni] = __builtin_amdgcn_mfma_f32_16x16x32_bf16(af[mi], bfr[ni], acc[mi][ni], 0, 0, 0);
    __syncthreads();
  }
#undef LOAD_TILE

#pragma unroll
  for (int mi = 0; mi < 4; ++mi) {
#pragma unroll
    for (int r = 0; r < 4; ++r) {
      int row = m0 + wm + mi * 16 + quad * 4 + r;
      if (row < M) {
#pragma unroll
        for (int ni = 0; ni < 4; ++ni) {
          int col = n0 + wn + ni * 16 + lm;
          float vv = acc[mi][ni][r];
          if (MODE == 0) {
            float o = vv + bias[col];
            Cf[(size_t)row * HD + col] = o;
            Cb[(size_t)row * HD + col] = f2bf(o);
          } else {
            Cb[(size_t)row * HD + col] = f2bf(vv);
          }
        }
      }
    }
  }
}

// ---------------- CSR build helpers ----------------
__global__ void k_setconst(int* __restrict__ p, int n, int v) {
  int i = blockIdx.x * blockDim.x + threadIdx.x;
  if (i < n) p[i] = v;
}

__global__ void k_count(const int* __restrict__ dst, int* __restrict__ cnt) {
  int e = blockIdx.x * blockDim.x + threadIdx.x;
  if (e < N_EDGES) atomicAdd(&cnt[dst[e]], 1);
}

__global__ __launch_bounds__(1024) void k_scanA(const int* __restrict__ cnt,
                                                int* __restrict__ sc, int* __restrict__ tot) {
  __shared__ int wsum[16];
  int g = blockIdx.x * 1024 + threadIdx.x;
  int lane = threadIdx.x & 63, w = threadIdx.x >> 6;
  int v = (g < N_NODES) ? cnt[g] : 0;
#pragma unroll
  for (int off = 1; off < 64; off <<= 1) {
    int u = __shfl_up(v, off);
    if (lane >= off) v += u;
  }
  if (lane == 63) wsum[w] = v;
  __syncthreads();
  if (w == 0) {
    int s = (lane < 16) ? wsum[lane] : 0;
#pragma unroll
    for (int off = 1; off < 16; off <<= 1) {
      int u = __shfl_up(s, off);
      if (lane >= off) s += u;
    }
    if (lane < 16) wsum[lane] = s;
  }
  __syncthreads();
  if (w > 0) v += wsum[w - 1];
  if (g < N_NODES) sc[g] = v;
  if (threadIdx.x == 1023) tot[blockIdx.x] = v;
}

__global__ void k_scanB(int* __restrict__ tot) {
  int lane = threadIdx.x;
  int v = (lane < 20) ? tot[lane] : 0;
#pragma unroll
  for (int off = 1; off < 32; off <<= 1) {
    int u = __shfl_up(v, off);
    if (lane >= off) v += u;
  }
  int e = __shfl_up(v, 1);
  if (lane == 0) e = 0;
  if (lane < 20) tot[lane] = e;
}

__global__ __launch_bounds__(1024) void k_scanC(const int* __restrict__ sc,
                                                const int* __restrict__ tot,
                                                int* __restrict__ row_ptr) {
  int g = blockIdx.x * 1024 + threadIdx.x;
  if (g < N_NODES) row_ptr[g + 1] = sc[g] + tot[blockIdx.x];
  if (g == 0) row_ptr[0] = 0;
}

__global__ void k_fill(const int* __restrict__ ei, const int* __restrict__ row_ptr,
                       int* __restrict__ fill, int* __restrict__ csr) {
  int idx = blockIdx.x * blockDim.x + threadIdx.x;
  if (idx >= E_TOT) return;
  int s, d;
  if (idx < N_EDGES) { s = ei[idx]; d = ei[N_EDGES + idx]; }
  else               { s = idx - N_EDGES; d = s; }       // self loops
  int p = atomicAdd(&fill[d], 1);
  csr[row_ptr[d] + p] = s;
}

// ---- per-node attn logits from bf16 xh ----
__global__ void k_attn(const ushort* __restrict__ xh,
                       const float* __restrict__ att_s,
                       const float* __restrict__ att_d,
                       float* __restrict__ al_s, float* __restrict__ al_d)
{
  int idx = blockIdx.x * blockDim.x + threadIdx.x;   // i*8+h
  if (idx >= N_NODES * NH) return;
  int hh = idx & 7;
  const ushort* row = xh + (size_t)(idx >> 3) * HD + hh * CH;
  const float4* a4  = (const float4*)(att_s + hh * CH);
  const float4* b4  = (const float4*)(att_d + hh * CH);
  float s = 0.f, d = 0.f;
#pragma unroll
  for (int q = 0; q < 8; ++q) {
    ushort4 xv = *(const ushort4*)(row + q * 4);
    float4 a = a4[q], b = b4[q];
    float v0 = bf2f(xv.x), v1 = bf2f(xv.y), v2 = bf2f(xv.z), v3 = bf2f(xv.w);
    s += v0 * a.x + v1 * a.y + v2 * a.z + v3 * a.w;
    d += v0 * b.x + v1 * b.y + v2 * b.z + v3 * b.w;
  }
  al_s[idx] = s;
  al_d[idx] = d;
}

// ---- aggregate: wave-per-node; bf16 xh gather; writes h (fp32) + h_bf (bf16) ----
__global__ __launch_bounds__(256) void k_aggregate(
    const ushort* __restrict__ xh, const float* __restrict__ al_s,
    const float* __restrict__ al_d, const int* __restrict__ row_ptr,
    const int* __restrict__ csr_src, const float* __restrict__ gat_b,
    const float* __restrict__ ln_g, const float* __restrict__ ln_b,
    float* __restrict__ h, ushort* __restrict__ h_bf)
{
  __shared__ float s_ea[4][64][9];
  __shared__ int   s_src[4][64];
  __shared__ int   s_deg[4];
  const int t = threadIdx.x;
  const int w = t >> 6, lane = t & 63;
  const int node = blockIdx.x * 4 + w;
  const int base = row_ptr[node];
  const int deg  = row_ptr[node + 1] - base;
  if (lane == 0) s_deg[w] = deg;
  __syncthreads();
  const int maxdeg = max(max(s_deg[0], s_deg[1]), max(s_deg[2], s_deg[3]));
  const int chunks = (maxdeg + 63) >> 6;

  float ald[8];
  {
    float4 a0 = *(const float4*)(al_d + (size_t)node * NH);
    float4 a1 = *(const float4*)(al_d + (size_t)node * NH + 4);
    ald[0] = a0.x; ald[1] = a0.y; ald[2] = a0.z; ald[3] = a0.w;
    ald[4] = a1.x; ald[5] = a1.y; ald[6] = a1.z; ald[7] = a1.w;
  }
  const int hh = lane >> 3;
  float4 acc = {0.f, 0.f, 0.f, 0.f};
  float den = 0.f;

  for (int c = 0; c < chunks; ++c) {
    const int cs = c << 6;
    int n = deg - cs; n = (n > 64) ? 64 : n;
    if (lane < n) {
      int s = csr_src[base + cs + lane];
      s_src[w][lane] = s;
      float4 b0 = *(const float4*)(al_s + (size_t)s * NH);
      float4 b1 = *(const float4*)(al_s + (size_t)s * NH + 4);
      float al[8] = {b0.x, b0.y, b0.z, b0.w, b1.x, b1.y, b1.z, b1.w};
#pragma unroll
      for (int q = 0; q < 8; ++q) {
        float a = al[q] + ald[q];
        a = fmaxf(a, 0.2f * a);
        s_ea[w][lane][q] = __expf(a);
      }
    }
    __syncthreads();
    for (int e = 0; e < n; ++e) {
      float wa = s_ea[w][e][hh];
      int s = s_src[w][e];
      den += wa;
      ushort4 xv = *(const ushort4*)(xh + (size_t)s * HD + lane * 4);
      acc.x = fmaf(wa, bf2f(xv.x), acc.x);
      acc.y = fmaf(wa, bf2f(xv.y), acc.y);
      acc.z = fmaf(wa, bf2f(xv.z), acc.z);
      acc.w = fmaf(wa, bf2f(xv.w), acc.w);
    }
    __syncthreads();
  }

  const float inv = 1.f / (den + 1e-16f);
  float4 g4 = *(const float4*)(gat_b + lane * 4);
  float4 v;
  v.x = acc.x * inv + g4.x;
  v.y = acc.y * inv + g4.y;
  v.z = acc.z * inv + g4.z;
  v.w = acc.w * inv + g4.w;
  v.x = (v.x > 0.f) ? v.x : (__expf(v.x) - 1.f);
  v.y = (v.y > 0.f) ? v.y : (__expf(v.y) - 1.f);
  v.z = (v.z > 0.f) ? v.z : (__expf(v.z) - 1.f);
  v.w = (v.w > 0.f) ? v.w : (__expf(v.w) - 1.f);
  float4 hres = *(const float4*)(h + (size_t)node * HD + lane * 4);
  v.x += hres.x; v.y += hres.y; v.z += hres.z; v.w += hres.w;

  float sum = v.x + v.y + v.z + v.w;
#pragma unroll
  for (int off = 32; off > 0; off >>= 1) sum += __shfl_xor(sum, off);
  const float mu = sum * (1.f / 256.f);
  float dx = v.x - mu, dy = v.y - mu, dz = v.z - mu, dw = v.w - mu;
  float ss = dx * dx + dy * dy + dz * dz + dw * dw;
#pragma unroll
  for (int off = 32; off > 0; off >>= 1) ss += __shfl_xor(ss, off);
  const float r = rsqrtf(ss * (1.f / 256.f) + 1e-5f);
  float4 lg = *(const float4*)(ln_g + lane * 4);
  float4 lb = *(const float4*)(ln_b + lane * 4);
  float4 o;
  o.x = dx * r * lg.x + lb.x;
  o.y = dy * r * lg.y + lb.y;
  o.z = dz * r * lg.z + lb.z;
  o.w = dw * r * lg.w + lb.w;
  *(float4*)(h + (size_t)node * HD + lane * 4) = o;
  ushort4 ob;
  ob.x = f2bf(o.x); ob.y = f2bf(o.y); ob.z = f2bf(o.z); ob.w = f2bf(o.w);
  *(ushort4*)(h_bf + (size_t)node * HD + lane * 4) = ob;
}

// qk[i] = sum_j key_W[i,j]*pool_q[j]; qk[256] = pool_q . key_b
__global__ __launch_bounds__(256) void k_qk(const float* __restrict__ key_W,
                                            const float* __restrict__ key_b,
                                            const float* __restrict__ pool_q,
                                            float* __restrict__ qk)
{
  __shared__ float sq[HD];
  int t = threadIdx.x;
  sq[t] = pool_q[t];
  __syncthreads();
  float a = 0.f;
  for (int j = 0; j < HD; ++j) a = fmaf(key_W[(size_t)t * HD + j], sq[j], a);
  qk[t] = a;
  if (t == 0) {
    float qb = 0.f;
    for (int j = 0; j < HD; ++j) qb += sq[j] * key_b[j];
    qk[HD] = qb;
  }
}

// ---- m1 = bf16(relu(onehot @ me_W1 + me_b1))  [32768 x 256] ----
__global__ __launch_bounds__(256) void k_mut1(
    const float* __restrict__ onehot, const float* __restrict__ W1,
    const float* __restrict__ b1, ushort* __restrict__ m1)
{
  __shared__ float s_oh[128][20];
  const int t = threadIdx.x;
  const int r0 = blockIdx.x * 128;
  float wreg[20];
#pragma unroll
  for (int j = 0; j < 20; ++j) wreg[j] = W1[j * HD + t];
  const float bb = b1[t];
  for (int i = t; i < 128 * 20; i += 256)
    s_oh[i / 20][i % 20] = onehot[(size_t)r0 * 20 + i];
  __syncthreads();
  for (int r = 0; r < 128; ++r) {
    float v = bb;
#pragma unroll
    for (int j = 0; j < 20; ++j) v = fmaf(s_oh[r][j], wreg[j], v);
    m1[(size_t)(r0 + r) * HD + t] = f2bf(fmaxf(v, 0.f));
  }
}

// ---- fused predict: mut2 GEMM (bf16 MFMA) + site gather + scores + softmax + pooled ----
// 64 rows (8 batch elems) x 256 cols per block; 4 waves, each = all 64 rows x 64-col slice.
__global__ __launch_bounds__(256, 2) void k_gemm_mut2(
    const ushort* __restrict__ m1, const ushort* __restrict__ W2T,
    const float* __restrict__ me_b2, const float* __restrict__ h,
    const int* __restrict__ sites, const unsigned char* __restrict__ mask8,
    const float* __restrict__ qk, float* __restrict__ pooled)
{
  __shared__ ushort As[64 * 32];     // 4 KB
  __shared__ ushort Bs[256 * 32];    // 16 KB
  __shared__ float s_part[64][4];
  __shared__ float s_w[64];
  __shared__ int   s_site[64];
  const int t = threadIdx.x;
  const int rows0 = blockIdx.x * 64;
  const int wave = t >> 6, lane = t & 63;
  const int wn = wave * 64;
  const int lm = lane & 15, quad = lane >> 4;

  if (t < 64) s_site[t] = sites[rows0 + t];

  f32x4 acc[4][4];                   // [mi = row-tile][ni = col-tile]
#pragma unroll
  for (int mi = 0; mi < 4; ++mi)
#pragma unroll
    for (int ni = 0; ni < 4; ++ni) acc[mi][ni] = (f32x4){0.f, 0.f, 0.f, 0.f};

  // staging geometry: A = 64 rows x 4 chunks (256 ops); B = 256 rows x 4 chunks (1024 ops)
  const int a_row = t >> 2, a_j = t & 3;
  uint4 pa;
  uint4 pbv[4];
#define LOAD_MUT(K0)                                                           \
  {                                                                            \
    pa = *(const uint4*)(m1 + (size_t)(rows0 + a_row) * HD + (K0) + a_j * 8);  \
    _Pragma("unroll")                                                          \
    for (int p = 0; p < 4; ++p) {                                              \
      int id = t + p * 256;                                                    \
      int row = id >> 2, j = id & 3;                                           \
      pbv[p] = *(const uint4*)(W2T + (size_t)row * HD + (K0) + j * 8);         \
    }                                                                          \
  }

  LOAD_MUT(0);
  for (int k0 = 0; k0 < HD; k0 += 32) {
    {
      int sw = (a_j ^ (a_row & 3)) * 8;
      *(uint4*)&As[a_row * 32 + sw] = pa;
#pragma unroll
      for (int p = 0; p < 4; ++p) {
        int id = t + p * 256;
        int row = id >> 2, j = id & 3;
        *(uint4*)&Bs[row * 32 + ((j ^ (row & 3)) * 8)] = pbv[p];
      }
    }
    __syncthreads();
    if (k0 + 32 < HD) LOAD_MUT(k0 + 32);

    bf16x8 af[4], bfr[4];
#pragma unroll
    for (int mi = 0; mi < 4; ++mi) {
      int row = mi * 16 + lm;
      af[mi] = *(const bf16x8*)&As[row * 32 + ((quad ^ (row & 3)) << 3)];
    }
#pragma unroll
    for (int ni = 0; ni < 4; ++ni) {
      int row = wn + ni * 16 + lm;
      bfr[ni] = *(const bf16x8*)&Bs[row * 32 + ((quad ^ (row & 3)) << 3)];
    }
#pragma unroll
    for (int mi = 0; mi < 4; ++mi)
#pragma unroll
      for (int ni = 0; ni < 4; ++ni)
        acc[mi][ni] = __builtin_amdgcn_mfma_f32_16x16x32_bf16(af[mi], bfr[ni], acc[mi][ni], 0, 0, 0);
    __syncthreads();
  }
#undef LOAD_MUT

  // epilogue: combined = acc + b2 + h[site]; score partials over this wave's 64 cols
  float pscore[4][4];
#pragma unroll
  for (int mi = 0; mi < 4; ++mi)
#pragma unroll
    for (int r = 0; r < 4; ++r) pscore[mi][r] = 0.f;

#pragma unroll
  for (int ni = 0; ni < 4; ++ni) {
    int col = wn + ni * 16 + lm;
    float qkc = qk[col];
    float b2c = me_b2[col];
#pragma unroll
    for (int mi = 0; mi < 4; ++mi) {
#pragma unroll
      for (int r = 0; r < 4; ++r) {
        int row = mi * 16 + quad * 4 + r;
        float c = acc[mi][ni][r] + b2c + h[(size_t)s_site[row] * HD + col];
        acc[mi][ni][r] = c;
        pscore[mi][r] = fmaf(c, qkc, pscore[mi][r]);
      }
    }
  }
  // reduce over the 16 lanes of each quad (cols within this wave)
#pragma unroll
  for (int mi = 0; mi < 4; ++mi)
#pragma unroll
    for (int r = 0; r < 4; ++r) {
      float p = pscore[mi][r];
      p += __shfl_xor(p, 8); p += __shfl_xor(p, 4);
      p += __shfl_xor(p, 2); p += __shfl_xor(p, 1);
      pscore[mi][r] = p;
    }
  if (lm == 0) {
#pragma unroll
    for (int mi = 0; mi < 4; ++mi)
#pragma unroll
      for (int r = 0; r < 4; ++r)
        s_part[mi * 16 + quad * 4 + r][wave] = pscore[mi][r];
  }
  __syncthreads();
  if (t < 64) {
    float s = s_part[t][0] + s_part[t][1] + s_part[t][2] + s_part[t][3];
    s = (s + qk[HD]) * 0.0625f;
    int grow = rows0 + t;
    bool mb;
    if (mask8[1] != 0) mb = mask8[grow] != 0;
    else               mb = ((const int*)mask8)[grow] != 0;
    s_w[t] = mb ? s : -INFINITY;
  }
  __syncthreads();
  if (t < 8) {
    float e[NM], mx = -INFINITY, den = 0.f;
#pragma unroll
    for (int m = 0; m < NM; ++m) mx = fmaxf(mx, s_w[t * NM + m]);
#pragma unroll
    for (int m = 0; m < NM; ++m) { e[m] = __expf(s_w[t * NM + m] - mx); den += e[m]; }
    float inv = 1.f / den;
#pragma unroll
    for (int m = 0; m < NM; ++m) s_w[t * NM + m] = e[m] * inv;
  }
  __syncthreads();
  // pooled: per mi, rows mi*16+quad*4+r; quad-pair combine gives full 8-row sums
#pragma unroll
  for (int ni = 0; ni < 4; ++ni) {
    int col = wn + ni * 16 + lm;
#pragma unroll
    for (int mi = 0; mi < 4; ++mi) {
      float pp = 0.f;
#pragma unroll
      for (int r = 0; r < 4; ++r)
        pp = fmaf(s_w[mi * 16 + quad * 4 + r], acc[mi][ni][r], pp);
      pp += __shfl_xor(pp, 16);          // combine quad pairs (0,1) and (2,3)
      int b = mi * 2 + (quad >> 1);
      if ((quad & 1) == 0)
        pooled[(size_t)(blockIdx.x * 8 + b) * HD + col] = pp;
    }
  }
}

// final MLP
__global__ __launch_bounds__(128) void k_mlp(
    const float* __restrict__ pooled, const float* __restrict__ W1,
    const float* __restrict__ b1, const float* __restrict__ W2,
    const float* __restrict__ b2, float* __restrict__ out)
{
  __shared__ float s_p[16][256];
  __shared__ float s_red[16][128];
  const int t = threadIdx.x;
  const int r0 = blockIdx.x * 16;
  for (int i = t; i < 16 * 256; i += 128) {
    int r = i >> 8, cc = i & 255;
    s_p[r][cc] = pooled[(size_t)(r0 + r) * HD + cc];
  }
  __syncthreads();
  float accm[16];
#pragma unroll
  for (int r = 0; r < 16; ++r) accm[r] = 0.f;
  for (int i = 0; i < 256; ++i) {
    float w = W1[(size_t)i * 128 + t];
#pragma unroll
    for (int r = 0; r < 16; ++r) accm[r] = fmaf(s_p[r][i], w, accm[r]);
  }
  float w2 = W2[t], bb1 = b1[t];
#pragma unroll
  for (int r = 0; r < 16; ++r) s_red[r][t] = fmaxf(accm[r] + bb1, 0.f) * w2;
  __syncthreads();
  if (t < 16) {
    float s = b2[0];
    for (int j = 0; j < 128; ++j) s += s_red[t][j];
    out[r0 + t] = s;
  }
}

extern "C" void kernel_launch(void* const* d_in, const int* in_sizes, int n_in,
                              void* d_out, int out_size, void* d_ws, size_t ws_size,
                              hipStream_t stream) {
  (void)in_sizes; (void)n_in; (void)out_size; (void)ws_size;
  const float* x        = (const float*)d_in[0];
  const int*   ei       = (const int*)d_in[1];
  const int*   sites    = (const int*)d_in[2];
  const float* onehot   = (const float*)d_in[3];
  const unsigned char* mask = (const unsigned char*)d_in[4];
  const float* in_W     = (const float*)d_in[5];
  const float* in_b     = (const float*)d_in[6];
  const float* gat_W    = (const float*)d_in[7];
  const float* att_src  = (const float*)d_in[8];
  const float* att_dst  = (const float*)d_in[9];
  const float* gat_b    = (const float*)d_in[10];
  const float* ln_g     = (const float*)d_in[11];
  const float* ln_b     = (const float*)d_in[12];
  const float* me_W1    = (const float*)d_in[13];
  const float* me_b1    = (const float*)d_in[14];
  const float* me_W2    = (const float*)d_in[15];
  const float* me_b2    = (const float*)d_in[16];
  const float* pool_q   = (const float*)d_in[17];
  const float* key_W    = (const float*)d_in[18];
  const float* key_b    = (const float*)d_in[19];
  const float* mlp_W1   = (const float*)d_in[20];
  const float* mlp_b1   = (const float*)d_in[21];
  const float* mlp_W2   = (const float*)d_in[22];
  const float* mlp_b2   = (const float*)d_in[23];
  float* outp = (float*)d_out;

  char* w = (char*)d_ws;
  float*  h       = (float*)(w + 0);                   // 20,480,000 B (live throughout)
  ushort* h_bf    = (ushort*)(w + 20480000);           // 10,240,000 B (layers only)
  ushort* xh_bf   = (ushort*)(w + 30720000);           // 10,240,000 B (layers only)
  float*  al_s    = (float*)(w + 40960000);            // 640,000 B (layers only)
  float*  al_d    = (float*)(w + 41600000);            // 640,000 B
  int*    row_ptr = (int*)  (w + 42240000);            // 80,128 B
  int*    cnt     = (int*)  (w + 42320128);            // 80,000 B
  int*    csr     = (int*)  (w + 42400128);            // 2,640,000 B
  float*  qk      = (float*)(w + 45040128);            // 1,280 B
  float*  pooled  = (float*)(w + 45041408);            // 4,194,304 B -> end 49,235,712
  // aliases in pooled region (dead before k_gemm_mut2 writes pooled):
  int*    sc      = (int*)pooled;                      // CSR scan scratch
  int*    tot     = sc + N_NODES;
  ushort* in_WT   = (ushort*)((char*)pooled + 131072); // 655,360 B
  ushort* gat_WT  = (ushort*)((char*)pooled + 786432); // 393,216 B
  // predict-phase aliases (dead after the 3 GAT layers):
  ushort* m1      = (ushort*)(w + 20480000);           // 16,777,216 B over h_bf+xh_bf
  ushort* me_W2T  = (ushort*)(w + 40960000);           // 131,072 B over al_s

  // transpose+convert weights to bf16 [N][K]
  k_wtrans<<<dim3(4, 20, 1), 256, 0, stream>>>(in_W, in_WT, 1280, HD, 0, 0);
  k_wtrans<<<dim3(4, 4, 3), 256, 0, stream>>>(gat_W, gat_WT, HD, HD, HD * HD, HD * HD);

  // h = x @ in_W + in_b  (bf16 MFMA, prefetch-pipelined; writes h fp32 + h_bf bf16)
  k_gemm_mfma<0><<<dim3(2, 157), 256, 0, stream>>>(x, in_WT, in_b, h, h_bf, N_NODES, 1280);

  // build CSR by dst (self-loop included via cnt init = 1)
  k_setconst<<<(N_NODES + 255) / 256, 256, 0, stream>>>(cnt, N_NODES, 1);
  k_count<<<(N_EDGES + 255) / 256, 256, 0, stream>>>(ei + N_EDGES, cnt);
  k_scanA<<<20, 1024, 0, stream>>>(cnt, sc, tot);
  k_scanB<<<1, 64, 0, stream>>>(tot);
  k_scanC<<<20, 1024, 0, stream>>>(sc, tot, row_ptr);
  k_setconst<<<(N_NODES + 255) / 256, 256, 0, stream>>>(cnt, N_NODES, 0);
  k_fill<<<(E_TOT + 255) / 256, 256, 0, stream>>>(ei, row_ptr, cnt, csr);

  for (int l = 0; l < 3; ++l) {
    k_gemm_mfma<1><<<dim3(2, 157), 256, 0, stream>>>(h_bf, gat_WT + (size_t)l * HD * HD,
                                                     nullptr, nullptr, xh_bf, N_NODES, HD);
    k_attn<<<(N_NODES * NH + 255) / 256, 256, 0, stream>>>(xh_bf, att_src + l * NH * CH,
                                                           att_dst + l * NH * CH, al_s, al_d);
    k_aggregate<<<N_NODES / 4, 256, 0, stream>>>(xh_bf, al_s, al_d, row_ptr, csr,
                                                 gat_b + l * HD, ln_g + l * HD, ln_b + l * HD,
                                                 h, h_bf);
  }

  // predict phase (h_bf/xh_bf/al_s now dead -> m1, me_W2T aliases)
  k_wtrans<<<dim3(4, 4, 1), 256, 0, stream>>>(me_W2, me_W2T, HD, HD, 0, 0);
  k_mut1<<<NB * NM / 128, 256, 0, stream>>>(onehot, me_W1, me_b1, m1);
  k_qk<<<1, 256, 0, stream>>>(key_W, key_b, pool_q, qk);
  k_gemm_mut2<<<NB * NM / 64, 256, 0, stream>>>(m1, me_W2T, me_b2, h, sites, mask, qk, pooled);
  k_mlp<<<NB / 16, 128, 0, stream>>>(pooled, mlp_W1, mlp_b1, mlp_W2, mlp_b2, outp);
}

// Round 6
// 621.689 us; speedup vs baseline: 1.1254x; 1.1254x over previous
//
#include <hip/hip_runtime.h>
#include <math.h>

#define N_NODES 20000
#define N_EDGES 640000
#define E_TOT   (N_EDGES + N_NODES)
#define HD 256
#define NH 8
#define CH 32
#define NB 4096
#define NM 8

typedef short bf16x8 __attribute__((ext_vector_type(8)));
typedef float f32x4  __attribute__((ext_vector_type(4)));

__device__ __forceinline__ ushort f2bf(float f) {   // RNE
  uint u = __float_as_uint(f);
  u += 0x7FFFu + ((u >> 16) & 1u);
  return (ushort)(u >> 16);
}
__device__ __forceinline__ float bf2f(ushort s) {
  return __uint_as_float(((uint)s) << 16);
}

// ---- weight transpose+convert: WT[n][k] = bf16(W[k][n]) ----
__global__ __launch_bounds__(256) void k_wtrans(
    const float* __restrict__ W, ushort* __restrict__ WT,
    int K, int N, int strideW, int strideWT)
{
  __shared__ float tile[64][65];
  const float* Wp = W + (size_t)blockIdx.z * strideW;
  ushort* WTp = WT + (size_t)blockIdx.z * strideWT;
  int n0 = blockIdx.x * 64, k0 = blockIdx.y * 64;
  int t = threadIdx.x;
  int c = t & 63, r0 = (t >> 6) * 16;
#pragma unroll
  for (int i = 0; i < 16; ++i)
    tile[r0 + i][c] = Wp[(size_t)(k0 + r0 + i) * N + n0 + c];
  __syncthreads();
#pragma unroll
  for (int i = 0; i < 16; ++i)
    WTp[(size_t)(n0 + r0 + i) * K + k0 + c] = f2bf(tile[c][r0 + i]);
}

// ---- bf16 MFMA GEMM: 64x128 tile (more blocks -> latency hiding), 4 waves 2x2 of 32x64 ----
// MODE 0: A fp32 (converted in staging); out = Cf fp32 (+bias) AND Cb bf16
// MODE 1: A bf16; out = Cb bf16 only
// Round-4 K-loop body (load -> LDS -> sync -> mfma -> sync); round-5 prefetch regressed.
template<int MODE>
__global__ __launch_bounds__(256, 4) void k_gemm_mfma(
    const void* __restrict__ Ain, const ushort* __restrict__ BT,
    const float* __restrict__ bias, float* __restrict__ Cf,
    ushort* __restrict__ Cb, int M, int K)
{
  __shared__ ushort As[64 * 32];    // 4 KB
  __shared__ ushort Bs[128 * 32];   // 8 KB
  const int t = threadIdx.x;
  const int n0 = blockIdx.x * 128;
  const int m0 = blockIdx.y * 64;
  const int wave = t >> 6, lane = t & 63;
  const int wm = (wave & 1) * 32, wn = (wave >> 1) * 64;
  const int lm = lane & 15, quad = lane >> 4;

  f32x4 acc[2][4];
#pragma unroll
  for (int mi = 0; mi < 2; ++mi)
#pragma unroll
    for (int ni = 0; ni < 4; ++ni) acc[mi][ni] = (f32x4){0.f, 0.f, 0.f, 0.f};

  const int a_row = t >> 2, a_j = t & 3;        // 64 rows x 4 k-chunks
  const int ar = min(m0 + a_row, M - 1);
  const int a_sw = (a_j ^ (a_row & 3)) * 8;

  for (int k0 = 0; k0 < K; k0 += 32) {
    // stage A
    if (MODE == 0) {
      const float* src = (const float*)Ain + (size_t)ar * K + k0 + a_j * 8;
      float4 u = *(const float4*)src;
      float4 v = *(const float4*)(src + 4);
      uint4 p;
      p.x = (uint)f2bf(u.x) | ((uint)f2bf(u.y) << 16);
      p.y = (uint)f2bf(u.z) | ((uint)f2bf(u.w) << 16);
      p.z = (uint)f2bf(v.x) | ((uint)f2bf(v.y) << 16);
      p.w = (uint)f2bf(v.z) | ((uint)f2bf(v.w) << 16);
      *(uint4*)&As[a_row * 32 + a_sw] = p;
    } else {
      const ushort* src = (const ushort*)Ain + (size_t)ar * K + k0 + a_j * 8;
      *(uint4*)&As[a_row * 32 + a_sw] = *(const uint4*)src;
    }
    // stage B (128 rows x 4 chunks = 512 ops, 2 per thread)
#pragma unroll
    for (int p = 0; p < 2; ++p) {
      int id = t + p * 256;
      int row = id >> 2, j = id & 3;
      *(uint4*)&Bs[row * 32 + ((j ^ (row & 3)) * 8)] =
          *(const uint4*)(BT + (size_t)(n0 + row) * K + k0 + j * 8);
    }
    __syncthreads();
    bf16x8 af[2], bfr[4];
#pragma unroll
    for (int mi = 0; mi < 2; ++mi) {
      int row = wm + mi * 16 + lm;
      af[mi] = *(const bf16x8*)&As[row * 32 + ((quad ^ (row & 3)) << 3)];
    }
#pragma unroll
    for (int ni = 0; ni < 4; ++ni) {
      int row = wn + ni * 16 + lm;
      bfr[ni] = *(const bf16x8*)&Bs[row * 32 + ((quad ^ (row & 3)) << 3)];
    }
#pragma unroll
    for (int mi = 0; mi < 2; ++mi)
#pragma unroll
      for (int ni = 0; ni < 4; ++ni)
        acc[mi][ni] = __builtin_amdgcn_mfma_f32_16x16x32_bf16(af[mi], bfr[ni], acc[mi][ni], 0, 0, 0);
    __syncthreads();
  }

#pragma unroll
  for (int mi = 0; mi < 2; ++mi) {
#pragma unroll
    for (int r = 0; r < 4; ++r) {
      int row = m0 + wm + mi * 16 + quad * 4 + r;
      if (row < M) {
#pragma unroll
        for (int ni = 0; ni < 4; ++ni) {
          int col = n0 + wn + ni * 16 + lm;
          float vv = acc[mi][ni][r];
          if (MODE == 0) {
            float o = vv + bias[col];
            Cf[(size_t)row * HD + col] = o;
            Cb[(size_t)row * HD + col] = f2bf(o);
          } else {
            Cb[(size_t)row * HD + col] = f2bf(vv);
          }
        }
      }
    }
  }
}

// ---------------- CSR build helpers ----------------
__global__ void k_setconst(int* __restrict__ p, int n, int v) {
  int i = blockIdx.x * blockDim.x + threadIdx.x;
  if (i < n) p[i] = v;
}

__global__ void k_count(const int* __restrict__ dst, int* __restrict__ cnt) {
  int e = blockIdx.x * blockDim.x + threadIdx.x;
  if (e < N_EDGES) atomicAdd(&cnt[dst[e]], 1);
}

__global__ __launch_bounds__(1024) void k_scanA(const int* __restrict__ cnt,
                                                int* __restrict__ sc, int* __restrict__ tot) {
  __shared__ int wsum[16];
  int g = blockIdx.x * 1024 + threadIdx.x;
  int lane = threadIdx.x & 63, w = threadIdx.x >> 6;
  int v = (g < N_NODES) ? cnt[g] : 0;
#pragma unroll
  for (int off = 1; off < 64; off <<= 1) {
    int u = __shfl_up(v, off);
    if (lane >= off) v += u;
  }
  if (lane == 63) wsum[w] = v;
  __syncthreads();
  if (w == 0) {
    int s = (lane < 16) ? wsum[lane] : 0;
#pragma unroll
    for (int off = 1; off < 16; off <<= 1) {
      int u = __shfl_up(s, off);
      if (lane >= off) s += u;
    }
    if (lane < 16) wsum[lane] = s;
  }
  __syncthreads();
  if (w > 0) v += wsum[w - 1];
  if (g < N_NODES) sc[g] = v;
  if (threadIdx.x == 1023) tot[blockIdx.x] = v;
}

__global__ void k_scanB(int* __restrict__ tot) {
  int lane = threadIdx.x;
  int v = (lane < 20) ? tot[lane] : 0;
#pragma unroll
  for (int off = 1; off < 32; off <<= 1) {
    int u = __shfl_up(v, off);
    if (lane >= off) v += u;
  }
  int e = __shfl_up(v, 1);
  if (lane == 0) e = 0;
  if (lane < 20) tot[lane] = e;
}

__global__ __launch_bounds__(1024) void k_scanC(const int* __restrict__ sc,
                                                const int* __restrict__ tot,
                                                int* __restrict__ row_ptr) {
  int g = blockIdx.x * 1024 + threadIdx.x;
  if (g < N_NODES) row_ptr[g + 1] = sc[g] + tot[blockIdx.x];
  if (g == 0) row_ptr[0] = 0;
}

__global__ void k_fill(const int* __restrict__ ei, const int* __restrict__ row_ptr,
                       int* __restrict__ fill, int* __restrict__ csr) {
  int idx = blockIdx.x * blockDim.x + threadIdx.x;
  if (idx >= E_TOT) return;
  int s, d;
  if (idx < N_EDGES) { s = ei[idx]; d = ei[N_EDGES + idx]; }
  else               { s = idx - N_EDGES; d = s; }       // self loops
  int p = atomicAdd(&fill[d], 1);
  csr[row_ptr[d] + p] = s;
}

// ---- per-node attn logits from bf16 xh ----
__global__ void k_attn(const ushort* __restrict__ xh,
                       const float* __restrict__ att_s,
                       const float* __restrict__ att_d,
                       float* __restrict__ al_s, float* __restrict__ al_d)
{
  int idx = blockIdx.x * blockDim.x + threadIdx.x;   // i*8+h
  if (idx >= N_NODES * NH) return;
  int hh = idx & 7;
  const ushort* row = xh + (size_t)(idx >> 3) * HD + hh * CH;
  const float4* a4  = (const float4*)(att_s + hh * CH);
  const float4* b4  = (const float4*)(att_d + hh * CH);
  float s = 0.f, d = 0.f;
#pragma unroll
  for (int q = 0; q < 8; ++q) {
    ushort4 xv = *(const ushort4*)(row + q * 4);
    float4 a = a4[q], b = b4[q];
    float v0 = bf2f(xv.x), v1 = bf2f(xv.y), v2 = bf2f(xv.z), v3 = bf2f(xv.w);
    s += v0 * a.x + v1 * a.y + v2 * a.z + v3 * a.w;
    d += v0 * b.x + v1 * b.y + v2 * b.z + v3 * b.w;
  }
  al_s[idx] = s;
  al_d[idx] = d;
}

// ---- aggregate: wave-per-node, 2 edges/iter (half-waves), 16B/lane gathers ----
// Half-wave hw = lane>>5 takes edges e+hw; lane32 = lane&31 owns channels lane32*8..+8.
__global__ __launch_bounds__(256) void k_aggregate(
    const ushort* __restrict__ xh, const float* __restrict__ al_s,
    const float* __restrict__ al_d, const int* __restrict__ row_ptr,
    const int* __restrict__ csr_src, const float* __restrict__ gat_b,
    const float* __restrict__ ln_g, const float* __restrict__ ln_b,
    float* __restrict__ h, ushort* __restrict__ h_bf)
{
  __shared__ float s_ea[4][64][9];   // [wave][edge][head] pad 9
  __shared__ int   s_src[4][64];
  __shared__ int   s_deg[4];
  const int t = threadIdx.x;
  const int w = t >> 6, lane = t & 63;
  const int lane32 = lane & 31, hw = lane >> 5;
  const int node = blockIdx.x * 4 + w;
  const int base = row_ptr[node];
  const int deg  = row_ptr[node + 1] - base;
  if (lane == 0) s_deg[w] = deg;
  __syncthreads();
  const int maxdeg = max(max(s_deg[0], s_deg[1]), max(s_deg[2], s_deg[3]));
  const int chunks = (maxdeg + 63) >> 6;

  float ald[8];
  {
    float4 a0 = *(const float4*)(al_d + (size_t)node * NH);
    float4 a1 = *(const float4*)(al_d + (size_t)node * NH + 4);
    ald[0] = a0.x; ald[1] = a0.y; ald[2] = a0.z; ald[3] = a0.w;
    ald[4] = a1.x; ald[5] = a1.y; ald[6] = a1.z; ald[7] = a1.w;
  }
  const int myhead = lane32 >> 2;          // head of this lane's 8 channels
  float acc[8] = {0.f, 0.f, 0.f, 0.f, 0.f, 0.f, 0.f, 0.f};
  float den = 0.f;

  for (int c = 0; c < chunks; ++c) {
    const int cs = c << 6;
    int n = deg - cs; n = (n > 64) ? 64 : n;   // may be <= 0 (idle wave)
    if (lane < n) {
      int s = csr_src[base + cs + lane];
      s_src[w][lane] = s;
      float4 b0 = *(const float4*)(al_s + (size_t)s * NH);
      float4 b1 = *(const float4*)(al_s + (size_t)s * NH + 4);
      float al[8] = {b0.x, b0.y, b0.z, b0.w, b1.x, b1.y, b1.z, b1.w};
#pragma unroll
      for (int q = 0; q < 8; ++q) {
        float a = al[q] + ald[q];
        a = fmaxf(a, 0.2f * a);                // leaky_relu(0.2)
        s_ea[w][lane][q] = __expf(a);
      }
    }
    __syncthreads();
    for (int e = 0; e < n; e += 2) {
      int my_e = e + hw;
      if (my_e < n) {
        int s = s_src[w][my_e];
        float wa = s_ea[w][my_e][myhead];
        den += wa;
        uint4 xv = *(const uint4*)(xh + (size_t)s * HD + lane32 * 8);
        ushort e0 = (ushort)(xv.x & 0xFFFF), e1 = (ushort)(xv.x >> 16);
        ushort e2 = (ushort)(xv.y & 0xFFFF), e3 = (ushort)(xv.y >> 16);
        ushort e4 = (ushort)(xv.z & 0xFFFF), e5 = (ushort)(xv.z >> 16);
        ushort e6 = (ushort)(xv.w & 0xFFFF), e7 = (ushort)(xv.w >> 16);
        acc[0] = fmaf(wa, bf2f(e0), acc[0]);
        acc[1] = fmaf(wa, bf2f(e1), acc[1]);
        acc[2] = fmaf(wa, bf2f(e2), acc[2]);
        acc[3] = fmaf(wa, bf2f(e3), acc[3]);
        acc[4] = fmaf(wa, bf2f(e4), acc[4]);
        acc[5] = fmaf(wa, bf2f(e5), acc[5]);
        acc[6] = fmaf(wa, bf2f(e6), acc[6]);
        acc[7] = fmaf(wa, bf2f(e7), acc[7]);
      }
    }
    __syncthreads();
  }

  // combine half-waves (both halves end with identical full sums)
#pragma unroll
  for (int q = 0; q < 8; ++q) acc[q] += __shfl_xor(acc[q], 32);
  den += __shfl_xor(den, 32);

  const float inv = 1.f / (den + 1e-16f);
  const int c8 = lane32 * 8;
  float4 g0 = *(const float4*)(gat_b + c8);
  float4 g1 = *(const float4*)(gat_b + c8 + 4);
  float gb[8] = {g0.x, g0.y, g0.z, g0.w, g1.x, g1.y, g1.z, g1.w};
  float4 h0 = *(const float4*)(h + (size_t)node * HD + c8);
  float4 h1 = *(const float4*)(h + (size_t)node * HD + c8 + 4);
  float hr[8] = {h0.x, h0.y, h0.z, h0.w, h1.x, h1.y, h1.z, h1.w};
  float v[8], sum8 = 0.f;
#pragma unroll
  for (int q = 0; q < 8; ++q) {
    float vv = acc[q] * inv + gb[q];
    vv = (vv > 0.f) ? vv : (__expf(vv) - 1.f);   // ELU
    vv += hr[q];                                  // residual
    v[q] = vv;
    sum8 += vv;
  }
#pragma unroll
  for (int off = 32; off > 0; off >>= 1) sum8 += __shfl_xor(sum8, off);
  const float mu = sum8 * (1.f / 512.f);          // each channel counted twice
  float ss8 = 0.f;
#pragma unroll
  for (int q = 0; q < 8; ++q) {
    v[q] -= mu;
    ss8 = fmaf(v[q], v[q], ss8);
  }
#pragma unroll
  for (int off = 32; off > 0; off >>= 1) ss8 += __shfl_xor(ss8, off);
  const float r = rsqrtf(ss8 * (1.f / 512.f) + 1e-5f);
  if (hw == 0) {
    float4 lg0 = *(const float4*)(ln_g + c8);
    float4 lg1 = *(const float4*)(ln_g + c8 + 4);
    float4 lb0 = *(const float4*)(ln_b + c8);
    float4 lb1 = *(const float4*)(ln_b + c8 + 4);
    float lg[8] = {lg0.x, lg0.y, lg0.z, lg0.w, lg1.x, lg1.y, lg1.z, lg1.w};
    float lb[8] = {lb0.x, lb0.y, lb0.z, lb0.w, lb1.x, lb1.y, lb1.z, lb1.w};
    float o[8];
#pragma unroll
    for (int q = 0; q < 8; ++q) o[q] = v[q] * r * lg[q] + lb[q];
    float4 of0 = {o[0], o[1], o[2], o[3]};
    float4 of1 = {o[4], o[5], o[6], o[7]};
    *(float4*)(h + (size_t)node * HD + c8) = of0;
    *(float4*)(h + (size_t)node * HD + c8 + 4) = of1;
    uint4 ob;
    ob.x = (uint)f2bf(o[0]) | ((uint)f2bf(o[1]) << 16);
    ob.y = (uint)f2bf(o[2]) | ((uint)f2bf(o[3]) << 16);
    ob.z = (uint)f2bf(o[4]) | ((uint)f2bf(o[5]) << 16);
    ob.w = (uint)f2bf(o[6]) | ((uint)f2bf(o[7]) << 16);
    *(uint4*)(h_bf + (size_t)node * HD + c8) = ob;
  }
}

// qk[i] = sum_j key_W[i,j]*pool_q[j]; qk[256] = pool_q . key_b
__global__ __launch_bounds__(256) void k_qk(const float* __restrict__ key_W,
                                            const float* __restrict__ key_b,
                                            const float* __restrict__ pool_q,
                                            float* __restrict__ qk)
{
  __shared__ float sq[HD];
  int t = threadIdx.x;
  sq[t] = pool_q[t];
  __syncthreads();
  float a = 0.f;
  for (int j = 0; j < HD; ++j) a = fmaf(key_W[(size_t)t * HD + j], sq[j], a);
  qk[t] = a;
  if (t == 0) {
    float qb = 0.f;
    for (int j = 0; j < HD; ++j) qb += sq[j] * key_b[j];
    qk[HD] = qb;
  }
}

// ---- m1 = bf16(relu(onehot @ me_W1 + me_b1))  [32768 x 256] ----
__global__ __launch_bounds__(256) void k_mut1(
    const float* __restrict__ onehot, const float* __restrict__ W1,
    const float* __restrict__ b1, ushort* __restrict__ m1)
{
  __shared__ float s_oh[128][20];
  const int t = threadIdx.x;
  const int r0 = blockIdx.x * 128;
  float wreg[20];
#pragma unroll
  for (int j = 0; j < 20; ++j) wreg[j] = W1[j * HD + t];
  const float bb = b1[t];
  for (int i = t; i < 128 * 20; i += 256)
    s_oh[i / 20][i % 20] = onehot[(size_t)r0 * 20 + i];
  __syncthreads();
  for (int r = 0; r < 128; ++r) {
    float v = bb;
#pragma unroll
    for (int j = 0; j < 20; ++j) v = fmaf(s_oh[r][j], wreg[j], v);
    m1[(size_t)(r0 + r) * HD + t] = f2bf(fmaxf(v, 0.f));
  }
}

// ---- fused predict: mut2 GEMM (bf16 MFMA) + site gather + scores + softmax + pooled ----
__global__ __launch_bounds__(256, 2) void k_gemm_mut2(
    const ushort* __restrict__ m1, const ushort* __restrict__ W2T,
    const float* __restrict__ me_b2, const float* __restrict__ h,
    const int* __restrict__ sites, const unsigned char* __restrict__ mask8,
    const float* __restrict__ qk, float* __restrict__ pooled)
{
  __shared__ ushort As[64 * 32];     // 4 KB
  __shared__ ushort Bs[256 * 32];    // 16 KB
  __shared__ float s_part[64][4];
  __shared__ float s_w[64];
  __shared__ int   s_site[64];
  const int t = threadIdx.x;
  const int rows0 = blockIdx.x * 64;
  const int wave = t >> 6, lane = t & 63;
  const int wn = wave * 64;
  const int lm = lane & 15, quad = lane >> 4;

  if (t < 64) s_site[t] = sites[rows0 + t];

  f32x4 acc[4][4];
#pragma unroll
  for (int mi = 0; mi < 4; ++mi)
#pragma unroll
    for (int ni = 0; ni < 4; ++ni) acc[mi][ni] = (f32x4){0.f, 0.f, 0.f, 0.f};

  const int a_row = t >> 2, a_j = t & 3;
  for (int k0 = 0; k0 < HD; k0 += 32) {
    *(uint4*)&As[a_row * 32 + ((a_j ^ (a_row & 3)) * 8)] =
        *(const uint4*)(m1 + (size_t)(rows0 + a_row) * HD + k0 + a_j * 8);
#pragma unroll
    for (int p = 0; p < 4; ++p) {
      int id = t + p * 256;
      int row = id >> 2, j = id & 3;
      *(uint4*)&Bs[row * 32 + ((j ^ (row & 3)) * 8)] =
          *(const uint4*)(W2T + (size_t)row * HD + k0 + j * 8);
    }
    __syncthreads();
    bf16x8 af[4], bfr[4];
#pragma unroll
    for (int mi = 0; mi < 4; ++mi) {
      int row = mi * 16 + lm;
      af[mi] = *(const bf16x8*)&As[row * 32 + ((quad ^ (row & 3)) << 3)];
    }
#pragma unroll
    for (int ni = 0; ni < 4; ++ni) {
      int row = wn + ni * 16 + lm;
      bfr[ni] = *(const bf16x8*)&Bs[row * 32 + ((quad ^ (row & 3)) << 3)];
    }
#pragma unroll
    for (int mi = 0; mi < 4; ++mi)
#pragma unroll
      for (int ni = 0; ni < 4; ++ni)
        acc[mi][ni] = __builtin_amdgcn_mfma_f32_16x16x32_bf16(af[mi], bfr[ni], acc[mi][ni], 0, 0, 0);
    __syncthreads();
  }

  float pscore[4][4];
#pragma unroll
  for (int mi = 0; mi < 4; ++mi)
#pragma unroll
    for (int r = 0; r < 4; ++r) pscore[mi][r] = 0.f;

#pragma unroll
  for (int ni = 0; ni < 4; ++ni) {
    int col = wn + ni * 16 + lm;
    float qkc = qk[col];
    float b2c = me_b2[col];
#pragma unroll
    for (int mi = 0; mi < 4; ++mi) {
#pragma unroll
      for (int r = 0; r < 4; ++r) {
        int row = mi * 16 + quad * 4 + r;
        float c = acc[mi][ni][r] + b2c + h[(size_t)s_site[row] * HD + col];
        acc[mi][ni][r] = c;
        pscore[mi][r] = fmaf(c, qkc, pscore[mi][r]);
      }
    }
  }
#pragma unroll
  for (int mi = 0; mi < 4; ++mi)
#pragma unroll
    for (int r = 0; r < 4; ++r) {
      float p = pscore[mi][r];
      p += __shfl_xor(p, 8); p += __shfl_xor(p, 4);
      p += __shfl_xor(p, 2); p += __shfl_xor(p, 1);
      pscore[mi][r] = p;
    }
  if (lm == 0) {
#pragma unroll
    for (int mi = 0; mi < 4; ++mi)
#pragma unroll
      for (int r = 0; r < 4; ++r)
        s_part[mi * 16 + quad * 4 + r][wave] = pscore[mi][r];
  }
  __syncthreads();
  if (t < 64) {
    float s = s_part[t][0] + s_part[t][1] + s_part[t][2] + s_part[t][3];
    s = (s + qk[HD]) * 0.0625f;
    int grow = rows0 + t;
    bool mb;
    if (mask8[1] != 0) mb = mask8[grow] != 0;
    else               mb = ((const int*)mask8)[grow] != 0;
    s_w[t] = mb ? s : -INFINITY;
  }
  __syncthreads();
  if (t < 8) {
    float e[NM], mx = -INFINITY, den = 0.f;
#pragma unroll
    for (int m = 0; m < NM; ++m) mx = fmaxf(mx, s_w[t * NM + m]);
#pragma unroll
    for (int m = 0; m < NM; ++m) { e[m] = __expf(s_w[t * NM + m] - mx); den += e[m]; }
    float inv = 1.f / den;
#pragma unroll
    for (int m = 0; m < NM; ++m) s_w[t * NM + m] = e[m] * inv;
  }
  __syncthreads();
#pragma unroll
  for (int ni = 0; ni < 4; ++ni) {
    int col = wn + ni * 16 + lm;
#pragma unroll
    for (int mi = 0; mi < 4; ++mi) {
      float pp = 0.f;
#pragma unroll
      for (int r = 0; r < 4; ++r)
        pp = fmaf(s_w[mi * 16 + quad * 4 + r], acc[mi][ni][r], pp);
      pp += __shfl_xor(pp, 16);
      int b = mi * 2 + (quad >> 1);
      if ((quad & 1) == 0)
        pooled[(size_t)(blockIdx.x * 8 + b) * HD + col] = pp;
    }
  }
}

// final MLP
__global__ __launch_bounds__(128) void k_mlp(
    const float* __restrict__ pooled, const float* __restrict__ W1,
    const float* __restrict__ b1, const float* __restrict__ W2,
    const float* __restrict__ b2, float* __restrict__ out)
{
  __shared__ float s_p[16][256];
  __shared__ float s_red[16][128];
  const int t = threadIdx.x;
  const int r0 = blockIdx.x * 16;
  for (int i = t; i < 16 * 256; i += 128) {
    int r = i >> 8, cc = i & 255;
    s_p[r][cc] = pooled[(size_t)(r0 + r) * HD + cc];
  }
  __syncthreads();
  float accm[16];
#pragma unroll
  for (int r = 0; r < 16; ++r) accm[r] = 0.f;
  for (int i = 0; i < 256; ++i) {
    float w = W1[(size_t)i * 128 + t];
#pragma unroll
    for (int r = 0; r < 16; ++r) accm[r] = fmaf(s_p[r][i], w, accm[r]);
  }
  float w2 = W2[t], bb1 = b1[t];
#pragma unroll
  for (int r = 0; r < 16; ++r) s_red[r][t] = fmaxf(accm[r] + bb1, 0.f) * w2;
  __syncthreads();
  if (t < 16) {
    float s = b2[0];
    for (int j = 0; j < 128; ++j) s += s_red[t][j];
    out[r0 + t] = s;
  }
}

extern "C" void kernel_launch(void* const* d_in, const int* in_sizes, int n_in,
                              void* d_out, int out_size, void* d_ws, size_t ws_size,
                              hipStream_t stream) {
  (void)in_sizes; (void)n_in; (void)out_size; (void)ws_size;
  const float* x        = (const float*)d_in[0];
  const int*   ei       = (const int*)d_in[1];
  const int*   sites    = (const int*)d_in[2];
  const float* onehot   = (const float*)d_in[3];
  const unsigned char* mask = (const unsigned char*)d_in[4];
  const float* in_W     = (const float*)d_in[5];
  const float* in_b     = (const float*)d_in[6];
  const float* gat_W    = (const float*)d_in[7];
  const float* att_src  = (const float*)d_in[8];
  const float* att_dst  = (const float*)d_in[9];
  const float* gat_b    = (const float*)d_in[10];
  const float* ln_g     = (const float*)d_in[11];
  const float* ln_b     = (const float*)d_in[12];
  const float* me_W1    = (const float*)d_in[13];
  const float* me_b1    = (const float*)d_in[14];
  const float* me_W2    = (const float*)d_in[15];
  const float* me_b2    = (const float*)d_in[16];
  const float* pool_q   = (const float*)d_in[17];
  const float* key_W    = (const float*)d_in[18];
  const float* key_b    = (const float*)d_in[19];
  const float* mlp_W1   = (const float*)d_in[20];
  const float* mlp_b1   = (const float*)d_in[21];
  const float* mlp_W2   = (const float*)d_in[22];
  const float* mlp_b2   = (const float*)d_in[23];
  float* outp = (float*)d_out;

  char* w = (char*)d_ws;
  float*  h       = (float*)(w + 0);                   // 20,480,000 B (live throughout)
  ushort* h_bf    = (ushort*)(w + 20480000);           // 10,240,000 B (layers only)
  ushort* xh_bf   = (ushort*)(w + 30720000);           // 10,240,000 B (layers only)
  float*  al_s    = (float*)(w + 40960000);            // 640,000 B (layers only)
  float*  al_d    = (float*)(w + 41600000);            // 640,000 B
  int*    row_ptr = (int*)  (w + 42240000);            // 80,128 B
  int*    cnt     = (int*)  (w + 42320128);            // 80,000 B
  int*    csr     = (int*)  (w + 42400128);            // 2,640,000 B
  float*  qk      = (float*)(w + 45040128);            // 1,280 B
  float*  pooled  = (float*)(w + 45041408);            // 4,194,304 B -> end 49,235,712
  // aliases in pooled region (dead before k_gemm_mut2 writes pooled):
  int*    sc      = (int*)pooled;
  int*    tot     = sc + N_NODES;
  ushort* in_WT   = (ushort*)((char*)pooled + 131072); // 655,360 B
  ushort* gat_WT  = (ushort*)((char*)pooled + 786432); // 393,216 B
  // predict-phase aliases (dead after the 3 GAT layers):
  ushort* m1      = (ushort*)(w + 20480000);           // 16,777,216 B over h_bf+xh_bf
  ushort* me_W2T  = (ushort*)(w + 40960000);           // 131,072 B over al_s

  // transpose+convert weights to bf16 [N][K]
  k_wtrans<<<dim3(4, 20, 1), 256, 0, stream>>>(in_W, in_WT, 1280, HD, 0, 0);
  k_wtrans<<<dim3(4, 4, 3), 256, 0, stream>>>(gat_W, gat_WT, HD, HD, HD * HD, HD * HD);

  // h = x @ in_W + in_b  (bf16 MFMA, 64x128 tiles; writes h fp32 + h_bf bf16)
  k_gemm_mfma<0><<<dim3(2, 313), 256, 0, stream>>>(x, in_WT, in_b, h, h_bf, N_NODES, 1280);

  // build CSR by dst (self-loop included via cnt init = 1)
  k_setconst<<<(N_NODES + 255) / 256, 256, 0, stream>>>(cnt, N_NODES, 1);
  k_count<<<(N_EDGES + 255) / 256, 256, 0, stream>>>(ei + N_EDGES, cnt);
  k_scanA<<<20, 1024, 0, stream>>>(cnt, sc, tot);
  k_scanB<<<1, 64, 0, stream>>>(tot);
  k_scanC<<<20, 1024, 0, stream>>>(sc, tot, row_ptr);
  k_setconst<<<(N_NODES + 255) / 256, 256, 0, stream>>>(cnt, N_NODES, 0);
  k_fill<<<(E_TOT + 255) / 256, 256, 0, stream>>>(ei, row_ptr, cnt, csr);

  for (int l = 0; l < 3; ++l) {
    k_gemm_mfma<1><<<dim3(2, 313), 256, 0, stream>>>(h_bf, gat_WT + (size_t)l * HD * HD,
                                                     nullptr, nullptr, xh_bf, N_NODES, HD);
    k_attn<<<(N_NODES * NH + 255) / 256, 256, 0, stream>>>(xh_bf, att_src + l * NH * CH,
                                                           att_dst + l * NH * CH, al_s, al_d);
    k_aggregate<<<N_NODES / 4, 256, 0, stream>>>(xh_bf, al_s, al_d, row_ptr, csr,
                                                 gat_b + l * HD, ln_g + l * HD, ln_b + l * HD,
                                                 h, h_bf);
  }

  // predict phase (h_bf/xh_bf/al_s now dead -> m1, me_W2T aliases)
  k_wtrans<<<dim3(4, 4, 1), 256, 0, stream>>>(me_W2, me_W2T, HD, HD, 0, 0);
  k_mut1<<<NB * NM / 128, 256, 0, stream>>>(onehot, me_W1, me_b1, m1);
  k_qk<<<1, 256, 0, stream>>>(key_W, key_b, pool_q, qk);
  k_gemm_mut2<<<NB * NM / 64, 256, 0, stream>>>(m1, me_W2T, me_b2, h, sites, mask, qk, pooled);
  k_mlp<<<NB / 16, 128, 0, stream>>>(pooled, mlp_W1, mlp_b1, mlp_W2, mlp_b2, outp);
}